// Round 4
// baseline (574.286 us; speedup 1.0000x reference)
//
#include <hip/hip_runtime.h>
#include <hip/hip_bf16.h>

typedef short short8v __attribute__((ext_vector_type(8)));
typedef float float4v __attribute__((ext_vector_type(4)));

constexpr int Bb = 64;    // batch
constexpr int Cc = 32;    // capsules (softmax axis)
constexpr int Nn = 1152;  // routes
constexpr int Oo = 64;    // out channels
constexpr int Ii = 64;    // in channels
constexpr int NCH = 32;   // n-chunks (grid.x)
constexpr int CHN = 36;   // n per chunk
constexpr int OT  = 32;   // o-tiles (grid.y), 2 o per tile
constexpr int COLS = 64;  // LDS cols per n: (c, o_local) = 32*2

__device__ __forceinline__ unsigned short bf16_rne(float f) {
    unsigned u = __float_as_uint(f);
    u += 0x7FFFu + ((u >> 16) & 1u);
    return (unsigned short)(u >> 16);
}
__device__ __forceinline__ float bf16_f(unsigned short h) {
    return __uint_as_float(((unsigned)h) << 16);
}
__device__ __forceinline__ float squash_elem(float s) {
    float sq = s * s;
    return (sq / (1.f + sq)) * s / sqrtf(sq + 1e-8f);
}

// ---- pre-split x into hi/lo bf16 planes (one-time, ~38 MB traffic) ---------
__global__ __launch_bounds__(256) void prep_x(const float* __restrict__ x,
                                              unsigned short* __restrict__ xh,
                                              unsigned short* __restrict__ xl) {
    size_t g = (size_t)blockIdx.x * 256 + threadIdx.x;  // one float4 per thread
    float4 v = ((const float4*)x)[g];
    float a[4] = {v.x, v.y, v.z, v.w};
    ushort4 H, L;
    unsigned short* hp = (unsigned short*)&H;
    unsigned short* lp = (unsigned short*)&L;
#pragma unroll
    for (int e = 0; e < 4; ++e) {
        unsigned short hb = bf16_rne(a[e]);
        hp[e] = hb;
        lp[e] = bf16_rne(a[e] - bf16_f(hb));
    }
    ((ushort4*)xh)[g] = H;
    ((ushort4*)xl)[g] = L;
}

// ---- fused pass: recompute u via split-bf16 MFMA, route, partial-reduce ----
// MODE 0: acc += u (iter-0 uniform weights; /32 applied in reduce)
// MODE 1: acc += softmax_c(u*V) * u
// Block: (n-chunk, o-pair). 64 b x 32 c x 2 o. LDS w tile XOR-swizzled (T2).
template <int MODE>
__global__ __launch_bounds__(256, 4) void caps_pass(
    const float* __restrict__ w, const unsigned short* __restrict__ xh,
    const unsigned short* __restrict__ xl, const float* __restrict__ V,
    float* __restrict__ part) {
    __shared__ unsigned short sh[2][COLS * 64];  // hi plane, [col][i] swizzled
    __shared__ unsigned short sl[2][COLS * 64];  // lo plane

    const int t = threadIdx.x;
    const int l = t & 63, wv = t >> 6;
    const int ch = blockIdx.x, ot = blockIdx.y;
    const int obase = ot * 2;
    const int kg = l >> 4;          // lane quarter (0..3): b sub-row / k-group
    const int lm = l & 15;
    const int n0 = ch * CHN;
    const int sw = (lm & 7) << 3;   // read-side XOR (ushort units): (row&7)*8

    // per-lane V: V[b][c][o], b = 16wv+4kg+r, c = 8t8+((l>>1)&7), o = obase+(l&1)
    float Vreg[4][4];
    if constexpr (MODE == 1) {
#pragma unroll
        for (int t8 = 0; t8 < 4; ++t8)
#pragma unroll
            for (int r = 0; r < 4; ++r) {
                int b = 16 * wv + 4 * kg + r;
                int c = 8 * t8 + ((l >> 1) & 7);
                int o = obase + (l & 1);
                Vreg[t8][r] = V[((size_t)b * Cc + c) * Oo + o];
            }
    }
    float accs[4][4];
#pragma unroll
    for (int t8 = 0; t8 < 4; ++t8)
#pragma unroll
        for (int r = 0; r < 4; ++r) accs[t8][r] = 0.f;

    // staging: per thread 4 chunks of 4 f32; col = (t>>4)+16k, i0 = (t&15)*4
    const int i0 = (t & 15) * 4;
    const int colb = t >> 4;
    float4 ld[4];

    auto issue = [&](int n) {
#pragma unroll
        for (int k = 0; k < 4; ++k) {
            int col = colb + 16 * k;
            int c = col >> 1, ol = col & 1;
            const float* g =
                w + (((size_t)c * Nn + n) * Oo + obase + ol) * Ii + i0;
            ld[k] = *(const float4*)g;
        }
    };
    auto writebuf = [&](int buf) {
#pragma unroll
        for (int k = 0; k < 4; ++k) {
            int col = colb + 16 * k;
            // write-side XOR swizzle: ushort off within row = i0 ^ ((col&7)*8)
            int off = col * 64 + (i0 ^ ((col & 7) << 3));
            float a[4] = {ld[k].x, ld[k].y, ld[k].z, ld[k].w};
            ushort4 H, L;
            unsigned short* hp = (unsigned short*)&H;
            unsigned short* lp = (unsigned short*)&L;
#pragma unroll
            for (int e = 0; e < 4; ++e) {
                unsigned short hb = bf16_rne(a[e]);
                hp[e] = hb;
                lp[e] = bf16_rne(a[e] - bf16_f(hb));
            }
            *(ushort4*)(&sh[buf][off]) = H;
            *(ushort4*)(&sl[buf][off]) = L;
        }
    };

    issue(n0);
    writebuf(0);
    __syncthreads();

    for (int j = 0; j < CHN; ++j) {
        const int n = n0 + j, cur = j & 1;
        if (j + 1 < CHN) issue(n0 + j + 1);

        // A-frags (x pre-split): lane row b = 16*wv + lm, k = kg*8 (+32)
        const size_t xoff = ((size_t)(16 * wv + lm) * Nn + n) * Ii + kg * 8;
        short8v ah0 = *(const short8v*)(xh + xoff);
        short8v al0 = *(const short8v*)(xl + xoff);
        short8v ah1 = *(const short8v*)(xh + xoff + 32);
        short8v al1 = *(const short8v*)(xl + xoff + 32);

        float u[4][4];
#pragma unroll
        for (int t8 = 0; t8 < 4; ++t8) {
            int row = 16 * t8 + lm;
            int c0 = row * 64 + ((kg * 8) ^ sw);          // i-chunk 0 (16B)
            int c1 = row * 64 + (((kg * 8) + 32) ^ sw);   // i-chunk 1 (16B)
            short8v bh0 = *(const short8v*)(&sh[cur][c0]);
            short8v bl0 = *(const short8v*)(&sl[cur][c0]);
            short8v bh1 = *(const short8v*)(&sh[cur][c1]);
            short8v bl1 = *(const short8v*)(&sl[cur][c1]);
            float4v a = {0.f, 0.f, 0.f, 0.f};
            a = __builtin_amdgcn_mfma_f32_16x16x32_bf16(ah0, bh0, a, 0, 0, 0);
            a = __builtin_amdgcn_mfma_f32_16x16x32_bf16(al0, bh0, a, 0, 0, 0);
            a = __builtin_amdgcn_mfma_f32_16x16x32_bf16(ah0, bl0, a, 0, 0, 0);
            a = __builtin_amdgcn_mfma_f32_16x16x32_bf16(ah1, bh1, a, 0, 0, 0);
            a = __builtin_amdgcn_mfma_f32_16x16x32_bf16(al1, bh1, a, 0, 0, 0);
            a = __builtin_amdgcn_mfma_f32_16x16x32_bf16(ah1, bl1, a, 0, 0, 0);
            u[t8][0] = a[0]; u[t8][1] = a[1]; u[t8][2] = a[2]; u[t8][3] = a[3];
        }

        if constexpr (MODE == 0) {
#pragma unroll
            for (int t8 = 0; t8 < 4; ++t8)
#pragma unroll
                for (int r = 0; r < 4; ++r) accs[t8][r] += u[t8][r];
        } else {
            // softmax over 32 c = 4 in-lane (t8) x 8 lanes (xor 2,4,8)
#pragma unroll
            for (int r = 0; r < 4; ++r) {
                float m = -1e30f;
#pragma unroll
                for (int t8 = 0; t8 < 4; ++t8)
                    m = fmaxf(m, u[t8][r] * Vreg[t8][r]);
                m = fmaxf(m, __shfl_xor(m, 2));
                m = fmaxf(m, __shfl_xor(m, 4));
                m = fmaxf(m, __shfl_xor(m, 8));
                float Z = 0.f;
#pragma unroll
                for (int t8 = 0; t8 < 4; ++t8) {
                    float e = __expf(u[t8][r] * Vreg[t8][r] - m);
                    Z += e;
                    u[t8][r] *= e;  // u now holds e*u
                }
                Z += __shfl_xor(Z, 2);
                Z += __shfl_xor(Z, 4);
                Z += __shfl_xor(Z, 8);
                float rz = 1.f / Z;
#pragma unroll
                for (int t8 = 0; t8 < 4; ++t8) accs[t8][r] += u[t8][r] * rz;
            }
        }

        if (j + 1 < CHN) {
            writebuf(cur ^ 1);
            __syncthreads();
        }
    }

    // write per-chunk partials: part[ch][b][c][o]
#pragma unroll
    for (int t8 = 0; t8 < 4; ++t8)
#pragma unroll
        for (int r = 0; r < 4; ++r) {
            int b = 16 * wv + 4 * kg + r;
            int c = 8 * t8 + ((l >> 1) & 7);
            int o = obase + (l & 1);
            part[(((size_t)ch * Bb + b) * Cc + c) * Oo + o] = accs[t8][r];
        }
}

// ---- reduce partials over chunks; squash; update V / write out -------------
__global__ void reduce_caps(const float* __restrict__ part,
                            float* __restrict__ V, float* __restrict__ out,
                            int mode) {
    int bc = blockIdx.x;       // b*32+c, 2048 blocks
    int o = threadIdx.x;       // 64
    size_t base = (size_t)bc * 64 + o;
    float s = 0.f;
    for (int c = 0; c < NCH; ++c) s += part[(size_t)c * (Bb * Cc * Oo) + base];
    if (mode == 0)      V[base] = squash_elem(s * (1.f / 32.f));
    else if (mode == 1) V[base] += squash_elem(s);
    else                out[base] = squash_elem(s);
}

extern "C" void kernel_launch(void* const* d_in, const int* in_sizes, int n_in,
                              void* d_out, int out_size, void* d_ws, size_t ws_size,
                              hipStream_t stream) {
    const float* x = (const float*)d_in[0];          // [64,1152,64]
    const float* w = (const float*)d_in[1];          // [32,1152,64,64]
    float* out = (float*)d_out;                      // [64,32,64]

    const size_t XE = (size_t)Bb * Nn * Ii;          // 4,718,592
    unsigned short* xh = (unsigned short*)d_ws;
    unsigned short* xl = xh + XE;
    float* part = (float*)(xl + XE);                 // 32*64*32*64 f32
    float* V = part + (size_t)NCH * Bb * Cc * Oo;

    prep_x<<<(int)(XE / 4 / 256), 256, 0, stream>>>(x, xh, xl);

    caps_pass<0><<<dim3(NCH, OT), 256, 0, stream>>>(w, xh, xl, nullptr, part);
    reduce_caps<<<Bb * Cc, 64, 0, stream>>>(part, V, out, 0);   // V = v0
    caps_pass<1><<<dim3(NCH, OT), 256, 0, stream>>>(w, xh, xl, V, part);
    reduce_caps<<<Bb * Cc, 64, 0, stream>>>(part, V, out, 1);   // V += v1
    caps_pass<1><<<dim3(NCH, OT), 256, 0, stream>>>(w, xh, xl, V, part);
    reduce_caps<<<Bb * Cc, 64, 0, stream>>>(part, V, out, 2);   // out = v2
}

// Round 5
// 495.335 us; speedup vs baseline: 1.1594x; 1.1594x over previous
//
#include <hip/hip_runtime.h>
#include <hip/hip_bf16.h>

typedef short short8v __attribute__((ext_vector_type(8)));
typedef float float4v __attribute__((ext_vector_type(4)));

constexpr int Bb = 64;    // batch
constexpr int Cc = 32;    // capsules (softmax axis)
constexpr int Nn = 1152;  // routes
constexpr int Oo = 64;    // out channels
constexpr int Ii = 64;    // in channels
constexpr int NCH = 32;   // n-chunks (grid.x)
constexpr int CHN = 36;   // n per chunk (even -> clean 2-unroll)
constexpr int OT  = 16;   // o-tiles (grid.y), 4 o per tile
constexpr int COLS = 128; // LDS cols per n: (c, o_local) = 32*4

__device__ __forceinline__ unsigned short bf16_rne(float f) {
    unsigned u = __float_as_uint(f);
    u += 0x7FFFu + ((u >> 16) & 1u);
    return (unsigned short)(u >> 16);
}
__device__ __forceinline__ float bf16_f(unsigned short h) {
    return __uint_as_float(((unsigned)h) << 16);
}
__device__ __forceinline__ float squash_elem(float s) {
    float sq = s * s;
    return (sq / (1.f + sq)) * s / sqrtf(sq + 1e-8f);
}

// ---- pre-split x into hi/lo bf16 planes (one-time, ~38 MB traffic) ---------
__global__ __launch_bounds__(256) void prep_x(const float* __restrict__ x,
                                              unsigned short* __restrict__ xh,
                                              unsigned short* __restrict__ xl) {
    size_t g = (size_t)blockIdx.x * 256 + threadIdx.x;  // one float4 per thread
    float4 v = ((const float4*)x)[g];
    float a[4] = {v.x, v.y, v.z, v.w};
    ushort4 H, L;
    unsigned short* hp = (unsigned short*)&H;
    unsigned short* lp = (unsigned short*)&L;
#pragma unroll
    for (int e = 0; e < 4; ++e) {
        unsigned short hb = bf16_rne(a[e]);
        hp[e] = hb;
        lp[e] = bf16_rne(a[e] - bf16_f(hb));
    }
    ((ushort4*)xh)[g] = H;
    ((ushort4*)xl)[g] = L;
}

// ---- fused pass: recompute u via split-bf16 MFMA, route, partial-reduce ----
// MODE 0: acc += u (iter-0 uniform weights; /32 applied in reduce)
// MODE 1: acc += softmax_c(u*V) * u
// Block (n-chunk, o-quad): 64 b x 32 c x 4 o. LDS XOR-swizzled (T2).
// Depth-2 register pipeline: ds_write consumes loads issued one full n earlier.
template <int MODE>
__global__ __launch_bounds__(256, 2) void caps_pass(
    const float* __restrict__ w, const unsigned short* __restrict__ xh,
    const unsigned short* __restrict__ xl, const float* __restrict__ V,
    float* __restrict__ part) {
    __shared__ unsigned short sh[2][COLS * 64];  // hi plane, [col][i^swz]
    __shared__ unsigned short sl[2][COLS * 64];  // lo plane

    const int t = threadIdx.x;
    const int l = t & 63, wv = t >> 6;
    const int ch = blockIdx.x, ot = blockIdx.y;
    const int obase = ot * 4;
    const int kg = l >> 4;          // lane quarter: b sub-row / k-group
    const int lm = l & 15;
    const int n0 = ch * CHN;
    const int sw = (lm & 7) << 3;   // read-side XOR (ushort units)

    // per-lane V: b = 16wv+4kg+r, c = 4t8+((l>>2)&3), o = obase+(l&3)
    float Vreg[8][4];
    if constexpr (MODE == 1) {
#pragma unroll
        for (int t8 = 0; t8 < 8; ++t8)
#pragma unroll
            for (int r = 0; r < 4; ++r) {
                int b = 16 * wv + 4 * kg + r;
                int c = 4 * t8 + ((l >> 2) & 3);
                int o = obase + (l & 3);
                Vreg[t8][r] = V[((size_t)b * Cc + c) * Oo + o];
            }
    }
    float4v acc4[8];   // MODE 0 accumulators (chained through MFMA C)
    float accs[8][4];  // MODE 1 accumulators
#pragma unroll
    for (int t8 = 0; t8 < 8; ++t8) {
        acc4[t8] = (float4v){0.f, 0.f, 0.f, 0.f};
#pragma unroll
        for (int r = 0; r < 4; ++r) accs[t8][r] = 0.f;
    }

    // staging: per thread 8 chunks of 4 f32; col = (t>>4)+16k, i0 = (t&15)*4
    const int i0 = (t & 15) * 4;
    const int colb = t >> 4;
    float4 L0[8], L1[8];

    auto issue = [&](int n, float4(&ld)[8]) {
#pragma unroll
        for (int k = 0; k < 8; ++k) {
            int col = colb + 16 * k;
            int c = col >> 2, olc = col & 3;
            ld[k] = *(const float4*)(
                w + (((size_t)c * Nn + n) * Oo + obase + olc) * Ii + i0);
        }
    };
    auto writebuf = [&](unsigned short* dh, unsigned short* dl,
                        const float4(&ld)[8]) {
#pragma unroll
        for (int k = 0; k < 8; ++k) {
            int col = colb + 16 * k;
            int off = col * 64 + (i0 ^ ((col & 7) << 3));  // write-side XOR
            float a[4] = {ld[k].x, ld[k].y, ld[k].z, ld[k].w};
            ushort4 H, L;
            unsigned short* hp = (unsigned short*)&H;
            unsigned short* lp = (unsigned short*)&L;
#pragma unroll
            for (int e = 0; e < 4; ++e) {
                unsigned short hb = bf16_rne(a[e]);
                hp[e] = hb;
                lp[e] = bf16_rne(a[e] - bf16_f(hb));
            }
            *(ushort4*)(dh + off) = H;
            *(ushort4*)(dl + off) = L;
        }
    };
    auto compute = [&](const unsigned short* bh_, const unsigned short* bl_,
                       int n) {
        // A-frags (x pre-split): lane row b = 16*wv + lm, k = kg*8 (+32)
        const size_t xoff = ((size_t)(16 * wv + lm) * Nn + n) * Ii + kg * 8;
        short8v ah0 = *(const short8v*)(xh + xoff);
        short8v al0 = *(const short8v*)(xl + xoff);
        short8v ah1 = *(const short8v*)(xh + xoff + 32);
        short8v al1 = *(const short8v*)(xl + xoff + 32);

        float u[8][4];
#pragma unroll
        for (int t8 = 0; t8 < 8; ++t8) {
            int row = 16 * t8 + lm;
            int c0 = row * 64 + ((kg * 8) ^ sw);
            int c1 = row * 64 + (((kg * 8) + 32) ^ sw);
            short8v bh0 = *(const short8v*)(bh_ + c0);
            short8v bl0 = *(const short8v*)(bl_ + c0);
            short8v bh1 = *(const short8v*)(bh_ + c1);
            short8v bl1 = *(const short8v*)(bl_ + c1);
            float4v a;
            if constexpr (MODE == 0) a = acc4[t8];
            else a = (float4v){0.f, 0.f, 0.f, 0.f};
            a = __builtin_amdgcn_mfma_f32_16x16x32_bf16(ah0, bh0, a, 0, 0, 0);
            a = __builtin_amdgcn_mfma_f32_16x16x32_bf16(al0, bh0, a, 0, 0, 0);
            a = __builtin_amdgcn_mfma_f32_16x16x32_bf16(ah0, bl0, a, 0, 0, 0);
            a = __builtin_amdgcn_mfma_f32_16x16x32_bf16(ah1, bh1, a, 0, 0, 0);
            a = __builtin_amdgcn_mfma_f32_16x16x32_bf16(al1, bh1, a, 0, 0, 0);
            a = __builtin_amdgcn_mfma_f32_16x16x32_bf16(ah1, bl1, a, 0, 0, 0);
            if constexpr (MODE == 0) {
                acc4[t8] = a;
            } else {
                u[t8][0] = a[0]; u[t8][1] = a[1];
                u[t8][2] = a[2]; u[t8][3] = a[3];
            }
        }
        if constexpr (MODE == 1) {
            // softmax over 32 c = 8 in-lane (t8) x 4 lanes (xor 4, 8)
#pragma unroll
            for (int r = 0; r < 4; ++r) {
                float m = -1e30f;
#pragma unroll
                for (int t8 = 0; t8 < 8; ++t8)
                    m = fmaxf(m, u[t8][r] * Vreg[t8][r]);
                m = fmaxf(m, __shfl_xor(m, 4));
                m = fmaxf(m, __shfl_xor(m, 8));
                float Z = 0.f;
#pragma unroll
                for (int t8 = 0; t8 < 8; ++t8) {
                    float e = __expf(u[t8][r] * Vreg[t8][r] - m);
                    Z += e;
                    u[t8][r] *= e;  // u now holds e*u
                }
                Z += __shfl_xor(Z, 4);
                Z += __shfl_xor(Z, 8);
                float rz = 1.f / Z;
#pragma unroll
                for (int t8 = 0; t8 < 8; ++t8) accs[t8][r] += u[t8][r] * rz;
            }
        }
    };

    // Prologue: buf0 <- n0 (via L0); L1 <- n0+1
    issue(n0, L0);
    writebuf(sh[0], sl[0], L0);
    issue(n0 + 1, L1);
    __syncthreads();

    // Invariant at top of even step j: buf0 holds n0+j, L1 holds n0+j+1.
    for (int j = 0; j < CHN; j += 2) {
        // even step
        writebuf(sh[1], sl[1], L1);            // buf1 <- n0+j+1 (loaded last j)
        if (j + 2 < CHN) issue(n0 + j + 2, L0);
        compute(sh[0], sl[0], n0 + j);
        __syncthreads();
        // odd step: buf1 holds n0+j+1, L0 holds n0+j+2
        if (j + 2 < CHN) writebuf(sh[0], sl[0], L0);
        if (j + 3 < CHN) issue(n0 + j + 3, L1);
        compute(sh[1], sl[1], n0 + j + 1);
        __syncthreads();
    }

    // write per-chunk partials: part[ch][b][c][o]
#pragma unroll
    for (int t8 = 0; t8 < 8; ++t8)
#pragma unroll
        for (int r = 0; r < 4; ++r) {
            int b = 16 * wv + 4 * kg + r;
            int c = 4 * t8 + ((l >> 2) & 3);
            int o = obase + (l & 3);
            float val = (MODE == 0) ? acc4[t8][r] : accs[t8][r];
            part[(((size_t)ch * Bb + b) * Cc + c) * Oo + o] = val;
        }
}

// ---- reduce partials over chunks; squash; update V / write out -------------
__global__ void reduce_caps(const float* __restrict__ part,
                            float* __restrict__ V, float* __restrict__ out,
                            int mode) {
    int bc = blockIdx.x;       // b*32+c, 2048 blocks
    int o = threadIdx.x;       // 64
    size_t base = (size_t)bc * 64 + o;
    float s = 0.f;
    for (int c = 0; c < NCH; ++c) s += part[(size_t)c * (Bb * Cc * Oo) + base];
    if (mode == 0)      V[base] = squash_elem(s * (1.f / 32.f));
    else if (mode == 1) V[base] += squash_elem(s);
    else                out[base] = squash_elem(s);
}

extern "C" void kernel_launch(void* const* d_in, const int* in_sizes, int n_in,
                              void* d_out, int out_size, void* d_ws, size_t ws_size,
                              hipStream_t stream) {
    const float* x = (const float*)d_in[0];          // [64,1152,64]
    const float* w = (const float*)d_in[1];          // [32,1152,64,64]
    float* out = (float*)d_out;                      // [64,32,64]

    const size_t XE = (size_t)Bb * Nn * Ii;          // 4,718,592
    unsigned short* xh = (unsigned short*)d_ws;
    unsigned short* xl = xh + XE;
    float* part = (float*)(xl + XE);                 // 32*64*32*64 f32
    float* V = part + (size_t)NCH * Bb * Cc * Oo;

    prep_x<<<(int)(XE / 4 / 256), 256, 0, stream>>>(x, xh, xl);

    caps_pass<0><<<dim3(NCH, OT), 256, 0, stream>>>(w, xh, xl, nullptr, part);
    reduce_caps<<<Bb * Cc, 64, 0, stream>>>(part, V, out, 0);   // V = v0
    caps_pass<1><<<dim3(NCH, OT), 256, 0, stream>>>(w, xh, xl, V, part);
    reduce_caps<<<Bb * Cc, 64, 0, stream>>>(part, V, out, 1);   // V += v1
    caps_pass<1><<<dim3(NCH, OT), 256, 0, stream>>>(w, xh, xl, V, part);
    reduce_caps<<<Bb * Cc, 64, 0, stream>>>(part, V, out, 2);   // out = v2
}